// Round 3
// baseline (16677.573 us; speedup 1.0000x reference)
//
#include <hip/hip_runtime.h>
#include <hip/hip_bf16.h>

#define Bb 128
#define Tt 1024
#define Ii 64
#define Hh 128

typedef float v2f __attribute__((ext_vector_type(2)));
static __device__ __forceinline__ v2f mk2(float x, float y) { v2f r; r.x = x; r.y = y; return r; }

static __device__ __forceinline__ float sigmoidf_(float x) {
  return 1.f / (1.f + expf(-x));
}

// ===========================================================================
// proj2: for chunk steps [t0, t0+Cc), all b: compute
//   Xc[tl][b][0:512)   = Y@W_g + b_g           (g = i,f,c,o)
//   Xc[tl][b][512+j]   = S3 = sum_m exp(v_m)   (aux softmax denominators)
//   Xc[tl][b][640+j]   = N3 = sum_m exp(v_m)*a_m
// where a_m = tanh(aux_m@auxW_m + auxb_m), v_m = a_m@W_a + b_a.
// Block = (b, 16 t-rows); grid.x = 128*(Cc/16) so block→XCD == b%8 (matches scan).
// ===========================================================================
__launch_bounds__(256, 4)
__global__ void proj2(const float* __restrict__ Y, const float* __restrict__ aux,
                      const float* __restrict__ Wi, const float* __restrict__ Wf,
                      const float* __restrict__ Wc, const float* __restrict__ Wo,
                      const float* __restrict__ bi, const float* __restrict__ bff,
                      const float* __restrict__ bc, const float* __restrict__ bo,
                      const float* __restrict__ auxW, const float* __restrict__ auxb,
                      const float* __restrict__ Wa, const float* __restrict__ ba,
                      float* __restrict__ Xc, int t0) {
  const int b   = blockIdx.x & 127;
  const int tt  = blockIdx.x >> 7;
  const int tg  = t0 + tt * 16;        // global first t of tile
  const int tlb = tt * 16;             // chunk-local first t of tile
  const int tau = threadIdx.x;
  const int j   = tau & 127;
  const int s   = tau >> 7;
  const int r0  = s * 8;               // this thread's 8 t-rows

  __shared__ float yin[16][64];
  __shared__ float ain[3][16][64];
  __shared__ float am0[16][128], am1[16][128], am2[16][128];

  ((float4*)&yin[0][0])[tau] = ((const float4*)(Y + ((size_t)b * Tt + tg) * Ii))[tau];
#pragma unroll
  for (int m = 0; m < 3; ++m)
    ((float4*)&ain[m][0][0])[tau] =
        ((const float4*)(aux + (((size_t)m * Bb + b) * Tt + tg) * Ii))[tau];
  __syncthreads();

  // ---------------- gate pair (i,f) ----------------
  {
    v2f acc[8];
#pragma unroll
    for (int r = 0; r < 8; ++r) acc[r] = mk2(0.f, 0.f);
#pragma unroll
    for (int k4 = 0; k4 < 16; ++k4) {
      v2f w0 = mk2(Wi[(k4*4+0)*Hh + j], Wf[(k4*4+0)*Hh + j]);
      v2f w1 = mk2(Wi[(k4*4+1)*Hh + j], Wf[(k4*4+1)*Hh + j]);
      v2f w2 = mk2(Wi[(k4*4+2)*Hh + j], Wf[(k4*4+2)*Hh + j]);
      v2f w3 = mk2(Wi[(k4*4+3)*Hh + j], Wf[(k4*4+3)*Hh + j]);
#pragma unroll
      for (int r = 0; r < 8; ++r) {
        float4 yv = *(const float4*)&yin[r0 + r][k4*4];
        acc[r] += w0 * yv.x;  acc[r] += w1 * yv.y;
        acc[r] += w2 * yv.z;  acc[r] += w3 * yv.w;
      }
    }
    float bij = bi[j], bfj = bff[j];
#pragma unroll
    for (int r = 0; r < 8; ++r) {
      size_t base = ((size_t)(tlb + r0 + r) * Bb + b) * 768;
      Xc[base + 0*Hh + j] = acc[r].x + bij;
      Xc[base + 1*Hh + j] = acc[r].y + bfj;
    }
  }
  // ---------------- gate pair (c,o) ----------------
  {
    v2f acc[8];
#pragma unroll
    for (int r = 0; r < 8; ++r) acc[r] = mk2(0.f, 0.f);
#pragma unroll
    for (int k4 = 0; k4 < 16; ++k4) {
      v2f w0 = mk2(Wc[(k4*4+0)*Hh + j], Wo[(k4*4+0)*Hh + j]);
      v2f w1 = mk2(Wc[(k4*4+1)*Hh + j], Wo[(k4*4+1)*Hh + j]);
      v2f w2 = mk2(Wc[(k4*4+2)*Hh + j], Wo[(k4*4+2)*Hh + j]);
      v2f w3 = mk2(Wc[(k4*4+3)*Hh + j], Wo[(k4*4+3)*Hh + j]);
#pragma unroll
      for (int r = 0; r < 8; ++r) {
        float4 yv = *(const float4*)&yin[r0 + r][k4*4];
        acc[r] += w0 * yv.x;  acc[r] += w1 * yv.y;
        acc[r] += w2 * yv.z;  acc[r] += w3 * yv.w;
      }
    }
    float bcj = bc[j], boj = bo[j];
#pragma unroll
    for (int r = 0; r < 8; ++r) {
      size_t base = ((size_t)(tlb + r0 + r) * Bb + b) * 768;
      Xc[base + 2*Hh + j] = acc[r].x + bcj;
      Xc[base + 3*Hh + j] = acc[r].y + boj;
    }
  }
  // ---------------- aux projections + tanh ----------------
  {
    float a0a[8], a1a[8], a2a[8];
#pragma unroll
    for (int r = 0; r < 8; ++r) { a0a[r] = 0.f; a1a[r] = 0.f; a2a[r] = 0.f; }
#pragma unroll
    for (int k4 = 0; k4 < 16; ++k4) {
      float w0a[4], w1a[4], w2a[4];
#pragma unroll
      for (int q = 0; q < 4; ++q) {
        int k = k4*4 + q;
        w0a[q] = auxW[(0*Ii + k)*Hh + j];
        w1a[q] = auxW[(1*Ii + k)*Hh + j];
        w2a[q] = auxW[(2*Ii + k)*Hh + j];
      }
#pragma unroll
      for (int r = 0; r < 8; ++r) {
        float4 x0 = *(const float4*)&ain[0][r0 + r][k4*4];
        float4 x1 = *(const float4*)&ain[1][r0 + r][k4*4];
        float4 x2 = *(const float4*)&ain[2][r0 + r][k4*4];
        a0a[r] += x0.x*w0a[0] + x0.y*w0a[1] + x0.z*w0a[2] + x0.w*w0a[3];
        a1a[r] += x1.x*w1a[0] + x1.y*w1a[1] + x1.z*w1a[2] + x1.w*w1a[3];
        a2a[r] += x2.x*w2a[0] + x2.y*w2a[1] + x2.z*w2a[2] + x2.w*w2a[3];
      }
    }
    float ab0 = auxb[0*Hh + j], ab1 = auxb[1*Hh + j], ab2 = auxb[2*Hh + j];
#pragma unroll
    for (int r = 0; r < 8; ++r) {
      am0[r0 + r][j] = tanhf(a0a[r] + ab0);
      am1[r0 + r][j] = tanhf(a1a[r] + ab1);
      am2[r0 + r][j] = tanhf(a2a[r] + ab2);
    }
  }
  __syncthreads();

  // ---------------- v_m = a_m @ W_a + b_a ; emit S3, N3 ----------------
  {
    float v0a[8], v1a[8], v2a[8];
#pragma unroll
    for (int r = 0; r < 8; ++r) { v0a[r] = 0.f; v1a[r] = 0.f; v2a[r] = 0.f; }
#pragma unroll
    for (int k4 = 0; k4 < 32; ++k4) {
      float wa0 = Wa[(k4*4+0)*Hh + j];
      float wa1 = Wa[(k4*4+1)*Hh + j];
      float wa2 = Wa[(k4*4+2)*Hh + j];
      float wa3 = Wa[(k4*4+3)*Hh + j];
#pragma unroll
      for (int r = 0; r < 8; ++r) {
        int t = r0 + r;
        float4 a0 = *(const float4*)&am0[t][k4*4];
        float4 a1 = *(const float4*)&am1[t][k4*4];
        float4 a2 = *(const float4*)&am2[t][k4*4];
        v0a[r] += a0.x*wa0 + a0.y*wa1 + a0.z*wa2 + a0.w*wa3;
        v1a[r] += a1.x*wa0 + a1.y*wa1 + a1.z*wa2 + a1.w*wa3;
        v2a[r] += a2.x*wa0 + a2.y*wa1 + a2.z*wa2 + a2.w*wa3;
      }
    }
    float baj = ba[j];
#pragma unroll
    for (int r = 0; r < 8; ++r) {
      int t = r0 + r;
      float e0 = expf(v0a[r] + baj);
      float e1 = expf(v1a[r] + baj);
      float e2 = expf(v2a[r] + baj);
      float a0j = am0[t][j], a1j = am1[t][j], a2j = am2[t][j];
      size_t base = ((size_t)(tlb + t) * Bb + b) * 768;
      Xc[base + 512 + j] = e0 + e1 + e2;
      Xc[base + 640 + j] = e0*a0j + e1*a1j + e2*a2j;
    }
  }
}

// ===========================================================================
// scan2: persistent per-row recurrence over chunk [t0, t0+Cc).
// 128 blocks x 1024 threads.  tau -> j=tau&127, s=(tau>>7)&1 (k-half),
// g=tau>>8 (gate).  Per-thread: wu[32] v2f (gate g, half s of U_g columns j),
// wa[8] v2f (slice r8 of W_a).  ~115 VGPR demand < 128 cap -> no spills.
// ===========================================================================
__launch_bounds__(1024, 4)
__global__ void scan2(const float* __restrict__ Xc,
                      const float* __restrict__ Ui, const float* __restrict__ Uf,
                      const float* __restrict__ Uc, const float* __restrict__ Uo,
                      const float* __restrict__ Wa, const float* __restrict__ ba,
                      float* __restrict__ state, float* __restrict__ out,
                      int t0, int Cc) {
  const int b   = blockIdx.x;
  const int tau = threadIdx.x;
  const int j   = tau & 127;
  const int s   = (tau >> 7) & 1;
  const int g   = tau >> 8;
  const int r8  = tau >> 7;          // 0..7 slice for the C~@W_a phase

  __shared__ float hbuf[Hh];
  __shared__ float act[4][Hh];       // i, f, C~, o
  __shared__ float redA[4][Hh];      // s=1 gate partials
  __shared__ float redC[8][Hh];      // W_a partials

  const float* Ug = (g == 0) ? Ui : (g == 1) ? Uf : (g == 2) ? Uc : Uo;

  v2f wu[32];
#pragma unroll
  for (int p = 0; p < 32; ++p) {
    int k = s * 64 + 2 * p;
    wu[p] = mk2(Ug[(size_t)k * Hh + j], Ug[(size_t)(k + 1) * Hh + j]);
  }
  v2f wa[8];
#pragma unroll
  for (int p = 0; p < 8; ++p) {
    int k = r8 * 16 + 2 * p;
    wa[p] = mk2(Wa[(size_t)k * Hh + j], Wa[(size_t)(k + 1) * Hh + j]);
  }
  const float ba_j = ba[j];

  // ---- state init ----
  float c = 0.f, h = 0.f;
  if (tau < Hh) {
    if (t0 > 0) { h = state[b * 256 + j]; c = state[b * 256 + 128 + j]; }
    hbuf[j] = h;
  }

  // ---- x-row registers: current + next (per-consumer direct loads) ----
  float xg_cur = 0.f, s3_cur = 0.f, n3_cur = 0.f;
  if (s == 0) xg_cur = Xc[((size_t)0 * Bb + b) * 768 + g * Hh + j];
  if (tau < Hh) {
    s3_cur = Xc[((size_t)0 * Bb + b) * 768 + 512 + j];
    n3_cur = Xc[((size_t)0 * Bb + b) * 768 + 640 + j];
  }
  __syncthreads();

  for (int tl = 0; tl < Cc; ++tl) {
    // prefetch next step's x values (consumed after next barrier cycle)
    float xg_nx = 0.f, s3_nx = 0.f, n3_nx = 0.f;
    if (tl + 1 < Cc) {
      size_t nb = ((size_t)(tl + 1) * Bb + b) * 768;
      if (s == 0) xg_nx = Xc[nb + g * Hh + j];
      if (tau < Hh) { s3_nx = Xc[nb + 512 + j]; n3_nx = Xc[nb + 640 + j]; }
    }

    // ---- Phase A: half-K gate partials (packed fp32) ----
    v2f acc = mk2(0.f, 0.f);
#pragma unroll
    for (int q4 = 0; q4 < 16; ++q4) {
      float4 h4 = *(const float4*)&hbuf[s * 64 + q4 * 4];
      acc += wu[2*q4]     * mk2(h4.x, h4.y);
      acc += wu[2*q4 + 1] * mk2(h4.z, h4.w);
    }
    float a = acc.x + acc.y;
    if (s) redA[g][j] = a;
    __syncthreads();  // B1

    // ---- Phase B: combine + activations ----
    if (s == 0) {
      float val = a + redA[g][j] + xg_cur;
      if (g == 2) act[2][j] = tanhf(val);
      else        act[g][j] = sigmoidf_(val);
    }
    __syncthreads();  // B2

    // ---- Phase C: v0 = C~ @ W_a (8-way K-sliced) ----
    v2f accc = mk2(0.f, 0.f);
#pragma unroll
    for (int q4 = 0; q4 < 4; ++q4) {
      float4 c4 = *(const float4*)&act[2][r8 * 16 + q4 * 4];
      accc += wa[2*q4]     * mk2(c4.x, c4.y);
      accc += wa[2*q4 + 1] * mk2(c4.z, c4.w);
    }
    redC[r8][j] = accc.x + accc.y;
    __syncthreads();  // B3

    // ---- Phase D: softmax-gate + cell update (threads 0..127) ----
    if (tau < Hh) {
      float v0 = ba_j;
#pragma unroll
      for (int r = 0; r < 8; ++r) v0 += redC[r][j];
      float e0 = expf(v0);
      float ct = act[2][j];
      float L  = (e0 * ct + n3_cur) / (e0 + s3_cur);
      c = act[1][j] * c + act[0][j] * L;
      h = act[3][j] * tanhf(c);
      hbuf[j] = h;
      out[16384 + ((size_t)b * Tt + (t0 + tl)) * Hh + j] = h;
      if (t0 + tl == Tt - 1) out[(size_t)b * Hh + j] = h;
    }
    __syncthreads();  // B4

    xg_cur = xg_nx;  s3_cur = s3_nx;  n3_cur = n3_nx;
  }

  if (tau < Hh) {
    state[b * 256 + j] = h;
    state[b * 256 + 128 + j] = c;
  }
}

// ===========================================================================
// Fallback (tiny ws): round-1 fused kernel, verbatim (passed, slow).
// ===========================================================================
__launch_bounds__(512, 2)
__global__ void fused_kernel(const float* __restrict__ Y,
                             const float* __restrict__ aux,
                             const float* __restrict__ Wi, const float* __restrict__ Ui,
                             const float* __restrict__ bi,
                             const float* __restrict__ Wf, const float* __restrict__ Uf,
                             const float* __restrict__ bfp,
                             const float* __restrict__ Wc, const float* __restrict__ Uc,
                             const float* __restrict__ bc,
                             const float* __restrict__ Wo, const float* __restrict__ Uo,
                             const float* __restrict__ bo,
                             const float* __restrict__ auxW, const float* __restrict__ auxb,
                             const float* __restrict__ Wa, const float* __restrict__ ba,
                             float* __restrict__ out) {
  const int b   = blockIdx.x;
  const int tau = threadIdx.x;
  const int j   = tau & 127;
  const int q   = tau >> 7;

  __shared__ float wG[4][Ii][Hh];
  __shared__ float xraw[2][4][Ii];
  __shared__ float hbuf[Hh];
  __shared__ float ctl[Hh];
  __shared__ float auxp[3][Hh];
  __shared__ float redG[4][4][Hh];
  __shared__ float redX[3][4][Hh];

  float wU[4][32];
  {
    const float* Us[4] = {Ui, Uf, Uc, Uo};
#pragma unroll
    for (int g = 0; g < 4; ++g)
#pragma unroll
      for (int k = 0; k < 32; ++k)
        wU[g][k] = Us[g][(q * 32 + k) * Hh + j];
  }
  float wA[32];
#pragma unroll
  for (int k = 0; k < 32; ++k) wA[k] = Wa[(q * 32 + k) * Hh + j];
  float wAux[3][16];
#pragma unroll
  for (int m = 0; m < 3; ++m)
#pragma unroll
    for (int k = 0; k < 16; ++k)
      wAux[m][k] = auxW[((size_t)m * Ii + (q * 16 + k)) * Hh + j];
  float bgate[4];
  {
    const float* Bs[4] = {bi, bfp, bc, bo};
#pragma unroll
    for (int g = 0; g < 4; ++g) bgate[g] = Bs[g][j];
  }
  const float abias = (q >= 1) ? auxb[(q - 1) * Hh + j] : 0.f;
  const float ba_j  = ba[j];

  {
    const float* Ws[4] = {Wi, Wf, Wc, Wo};
#pragma unroll
    for (int g = 0; g < 4; ++g) {
      const float4* src = (const float4*)Ws[g];
      float4* dst = (float4*)&wG[g][0][0];
#pragma unroll
      for (int r = 0; r < 4; ++r) dst[tau + r * 512] = src[tau + r * 512];
    }
  }

  if (tau < Hh) hbuf[tau] = 0.f;
  float c = 0.f;

  const bool ldr = (tau < 64);
  const int  m4  = tau >> 4;
  const int  idx = tau & 15;
  const float* srcbase = nullptr;
  float4 xn = make_float4(0.f, 0.f, 0.f, 0.f);
  if (ldr) {
    srcbase = (m4 == 0) ? (Y + ((size_t)b * Tt) * Ii)
                        : (aux + (((size_t)(m4 - 1) * Bb + b) * Tt) * Ii);
    float4 x0 = ((const float4*)srcbase)[idx];
    ((float4*)&xraw[0][0][0])[tau] = x0;
    xn = ((const float4*)(srcbase + Ii))[idx];
  }
  __syncthreads();

  for (int t = 0; t < Tt; ++t) {
    const int p = t & 1;
    float aG0 = 0.f, aG1 = 0.f, aG2 = 0.f, aG3 = 0.f;
#pragma unroll
    for (int kk = 0; kk < 8; ++kk) {
      float4 hv = *(const float4*)&hbuf[q * 32 + kk * 4];
      aG0 += hv.x*wU[0][kk*4] + hv.y*wU[0][kk*4+1] + hv.z*wU[0][kk*4+2] + hv.w*wU[0][kk*4+3];
      aG1 += hv.x*wU[1][kk*4] + hv.y*wU[1][kk*4+1] + hv.z*wU[1][kk*4+2] + hv.w*wU[1][kk*4+3];
      aG2 += hv.x*wU[2][kk*4] + hv.y*wU[2][kk*4+1] + hv.z*wU[2][kk*4+2] + hv.w*wU[2][kk*4+3];
      aG3 += hv.x*wU[3][kk*4] + hv.y*wU[3][kk*4+1] + hv.z*wU[3][kk*4+2] + hv.w*wU[3][kk*4+3];
    }
#pragma unroll
    for (int kk = 0; kk < 4; ++kk) {
      const int k0 = q * 16 + kk * 4;
      float4 yv = *(const float4*)&xraw[p][0][k0];
      aG0 += yv.x*wG[0][k0][j] + yv.y*wG[0][k0+1][j] + yv.z*wG[0][k0+2][j] + yv.w*wG[0][k0+3][j];
      aG1 += yv.x*wG[1][k0][j] + yv.y*wG[1][k0+1][j] + yv.z*wG[1][k0+2][j] + yv.w*wG[1][k0+3][j];
      aG2 += yv.x*wG[2][k0][j] + yv.y*wG[2][k0+1][j] + yv.z*wG[2][k0+2][j] + yv.w*wG[2][k0+3][j];
      aG3 += yv.x*wG[3][k0][j] + yv.y*wG[3][k0+1][j] + yv.z*wG[3][k0+2][j] + yv.w*wG[3][k0+3][j];
    }
    float sA0 = 0.f, sA1 = 0.f, sA2 = 0.f;
#pragma unroll
    for (int kk = 0; kk < 4; ++kk) {
      const int k0 = q * 16 + kk * 4;
      float4 a0v = *(const float4*)&xraw[p][1][k0];
      float4 a1v = *(const float4*)&xraw[p][2][k0];
      float4 a2v = *(const float4*)&xraw[p][3][k0];
      sA0 += a0v.x*wAux[0][kk*4] + a0v.y*wAux[0][kk*4+1] + a0v.z*wAux[0][kk*4+2] + a0v.w*wAux[0][kk*4+3];
      sA1 += a1v.x*wAux[1][kk*4] + a1v.y*wAux[1][kk*4+1] + a1v.z*wAux[1][kk*4+2] + a1v.w*wAux[1][kk*4+3];
      sA2 += a2v.x*wAux[2][kk*4] + a2v.y*wAux[2][kk*4+1] + a2v.z*wAux[2][kk*4+2] + a2v.w*wAux[2][kk*4+3];
    }
    redG[0][q][j] = aG0;  redG[1][q][j] = aG1;
    redG[2][q][j] = aG2;  redG[3][q][j] = aG3;
    redX[0][q][j] = sA0;  redX[1][q][j] = sA1;  redX[2][q][j] = sA2;
    __syncthreads();

    if (q == 0) {
      float pi = bgate[0] + redG[0][0][j] + redG[0][1][j] + redG[0][2][j] + redG[0][3][j];
      float pf = bgate[1] + redG[1][0][j] + redG[1][1][j] + redG[1][2][j] + redG[1][3][j];
      float pc = bgate[2] + redG[2][0][j] + redG[2][1][j] + redG[2][2][j] + redG[2][3][j];
      float po = bgate[3] + redG[3][0][j] + redG[3][1][j] + redG[3][2][j] + redG[3][3][j];
      act_dummy: ;
      float ig = sigmoidf_(pi);
      float fg = sigmoidf_(pf);
      float og = sigmoidf_(po);
      ctl[j] = tanhf(pc);
      redG[0][0][j] = ig;  redG[1][0][j] = fg;  redG[3][0][j] = og;
    } else {
      const int m = q - 1;
      float v = abias + redX[m][0][j] + redX[m][1][j] + redX[m][2][j] + redX[m][3][j];
      auxp[m][j] = tanhf(v);
    }
    if (ldr) {
      ((float4*)&xraw[p ^ 1][0][0])[tau] = xn;
      if (t + 2 < Tt) xn = ((const float4*)(srcbase + (size_t)(t + 2) * Ii))[idx];
    }
    __syncthreads();

    float sS0 = 0.f, sS1 = 0.f, sS2 = 0.f, sS3 = 0.f;
#pragma unroll
    for (int kk = 0; kk < 8; ++kk) {
      const int k0 = q * 32 + kk * 4;
      float4 c0 = *(const float4*)&ctl[k0];
      float4 c1 = *(const float4*)&auxp[0][k0];
      float4 c2 = *(const float4*)&auxp[1][k0];
      float4 c3 = *(const float4*)&auxp[2][k0];
      sS0 += c0.x*wA[kk*4] + c0.y*wA[kk*4+1] + c0.z*wA[kk*4+2] + c0.w*wA[kk*4+3];
      sS1 += c1.x*wA[kk*4] + c1.y*wA[kk*4+1] + c1.z*wA[kk*4+2] + c1.w*wA[kk*4+3];
      sS2 += c2.x*wA[kk*4] + c2.y*wA[kk*4+1] + c2.z*wA[kk*4+2] + c2.w*wA[kk*4+3];
      sS3 += c3.x*wA[kk*4] + c3.y*wA[kk*4+1] + c3.z*wA[kk*4+2] + c3.w*wA[kk*4+3];
    }
    __syncthreads();
    redX[0][q][j] = sS1;  redX[1][q][j] = sS2;  redX[2][q][j] = sS3;
    redG[2][q][j] = sS0;
    __syncthreads();

    if (q == 0) {
      float v0 = ba_j + redG[2][0][j] + redG[2][1][j] + redG[2][2][j] + redG[2][3][j];
      float v1 = ba_j + redX[0][0][j] + redX[0][1][j] + redX[0][2][j] + redX[0][3][j];
      float v2 = ba_j + redX[1][0][j] + redX[1][1][j] + redX[1][2][j] + redX[1][3][j];
      float v3 = ba_j + redX[2][0][j] + redX[2][1][j] + redX[2][2][j] + redX[2][3][j];
      float mx = fmaxf(fmaxf(v0, v1), fmaxf(v2, v3));
      float e0 = expf(v0 - mx), e1 = expf(v1 - mx), e2 = expf(v2 - mx), e3 = expf(v3 - mx);
      float inv = 1.f / (e0 + e1 + e2 + e3);
      float L = (e0 * ctl[j] + e1 * auxp[0][j] + e2 * auxp[1][j] + e3 * auxp[2][j]) * inv;
      float ig = redG[0][0][j], fg = redG[1][0][j], og = redG[3][0][j];
      c = fg * c + ig * L;
      float h = og * tanhf(c);
      hbuf[j] = h;
      out[16384 + ((size_t)b * Tt + t) * Hh + j] = h;
      if (t == Tt - 1) out[(size_t)b * Hh + j] = h;
    }
    __syncthreads();
  }
}

// ===========================================================================
extern "C" void kernel_launch(void* const* d_in, const int* in_sizes, int n_in,
                              void* d_out, int out_size, void* d_ws, size_t ws_size,
                              hipStream_t stream) {
  (void)in_sizes; (void)n_in; (void)out_size;
  const float* Y     = (const float*)d_in[0];
  const float* aux   = (const float*)d_in[1];
  const float* W_i   = (const float*)d_in[2];
  const float* U_i   = (const float*)d_in[3];
  const float* b_i   = (const float*)d_in[4];
  const float* W_f   = (const float*)d_in[5];
  const float* U_f   = (const float*)d_in[6];
  const float* b_f   = (const float*)d_in[7];
  const float* W_c   = (const float*)d_in[8];
  const float* U_c   = (const float*)d_in[9];
  const float* b_c   = (const float*)d_in[10];
  const float* W_o   = (const float*)d_in[11];
  const float* U_o   = (const float*)d_in[12];
  const float* b_o   = (const float*)d_in[13];
  const float* aux_W = (const float*)d_in[14];
  const float* aux_b = (const float*)d_in[15];
  const float* W_a   = (const float*)d_in[16];
  const float* b_a   = (const float*)d_in[17];
  float* out = (float*)d_out;

  // pick chunk size C (steps) that fits ws: Xc = C*128*768*4 bytes + 128KB state
  int C = 0;
  const int cands[3] = {64, 32, 16};
  for (int i = 0; i < 3; ++i) {
    size_t need = (size_t)cands[i] * Bb * 768 * sizeof(float) + 131072;
    if (d_ws != nullptr && ws_size >= need) { C = cands[i]; break; }
  }

  if (C > 0) {
    float* Xc    = (float*)d_ws;
    float* state = (float*)((char*)d_ws + (size_t)C * Bb * 768 * sizeof(float));
    for (int t0 = 0; t0 < Tt; t0 += C) {
      int Cc = (Tt - t0 < C) ? (Tt - t0) : C;
      proj2<<<dim3(Bb * (Cc / 16)), dim3(256), 0, stream>>>(
          Y, aux, W_i, W_f, W_c, W_o, b_i, b_f, b_c, b_o,
          aux_W, aux_b, W_a, b_a, Xc, t0);
      scan2<<<dim3(Bb), dim3(1024), 0, stream>>>(
          Xc, U_i, U_f, U_c, U_o, W_a, b_a, state, out, t0, Cc);
    }
  } else {
    fused_kernel<<<dim3(Bb), dim3(512), 0, stream>>>(
        Y, aux, W_i, U_i, b_i, W_f, U_f, b_f, W_c, U_c, b_c,
        W_o, U_o, b_o, aux_W, aux_b, W_a, b_a, out);
  }
}

// Round 4
// 3352.974 us; speedup vs baseline: 4.9740x; 4.9740x over previous
//
#include <hip/hip_runtime.h>
#include <hip/hip_bf16.h>

#define Bb 128
#define Tt 1024
#define Ii 64
#define Hh 128

typedef float v2f __attribute__((ext_vector_type(2)));
static __device__ __forceinline__ v2f mk2(float x, float y) { v2f r; r.x = x; r.y = y; return r; }
static __device__ __forceinline__ float sigmoidf_(float x) { return 1.f / (1.f + expf(-x)); }

// Xc row layout per (t,b): [0:512) gate preacts (i|f|c|o, bias included),
// [512:640) S3 = sum_m exp(v_m), [640:768) N3 = sum_m exp(v_m)*a_m.

// ===========================================================================
// P1: gate preacts for chunk.  Block = (b, 32 t-rows).  All weights staged in
// LDS once per block; inner loops read LDS only.
// ===========================================================================
__launch_bounds__(256, 1)
__global__ void p1_gates(const float* __restrict__ Y,
                         const float* __restrict__ Wi, const float* __restrict__ Wf,
                         const float* __restrict__ Wc, const float* __restrict__ Wo,
                         const float* __restrict__ bi, const float* __restrict__ bff,
                         const float* __restrict__ bc, const float* __restrict__ bo,
                         float* __restrict__ Xc, int t0) {
  const int b   = blockIdx.x & 127;
  const int tt  = blockIdx.x >> 7;
  const int tg  = t0 + tt * 32;
  const int tlb = tt * 32;
  const int tau = threadIdx.x;

  __shared__ float wlds[64][512];   // 128 KB: [k][g*128+j]
  __shared__ float yin[32][64];     // 8 KB
  __shared__ float blds[512];       // 2 KB

  {
    const float* Ws[4] = {Wi, Wf, Wc, Wo};
#pragma unroll
    for (int g = 0; g < 4; ++g) {
      const float4* src = (const float4*)Ws[g];
#pragma unroll
      for (int it = 0; it < 8; ++it) {
        int idx = it * 256 + tau;          // 0..2047 float4s of a 64x128 matrix
        int k = idx >> 5, c4 = idx & 31;
        *(float4*)&wlds[k][g * 128 + c4 * 4] = src[idx];
      }
    }
    if (tau < 128) {
      blds[0 * 128 + tau] = bi[tau];
      blds[1 * 128 + tau] = bff[tau];
      blds[2 * 128 + tau] = bc[tau];
      blds[3 * 128 + tau] = bo[tau];
    }
    const float4* ys = (const float4*)(Y + ((size_t)b * Tt + tg) * Ii);
    ((float4*)&yin[0][0])[tau]       = ys[tau];
    ((float4*)&yin[0][0])[tau + 256] = ys[tau + 256];
  }
  __syncthreads();

  const int cp = tau;                 // col pair: cols 2cp, 2cp+1 of 512
  v2f acc[32];
#pragma unroll
  for (int r = 0; r < 32; ++r) acc[r] = mk2(0.f, 0.f);

#pragma unroll
  for (int k4 = 0; k4 < 16; ++k4) {
    v2f w0 = *(const v2f*)&wlds[k4 * 4 + 0][2 * cp];
    v2f w1 = *(const v2f*)&wlds[k4 * 4 + 1][2 * cp];
    v2f w2 = *(const v2f*)&wlds[k4 * 4 + 2][2 * cp];
    v2f w3 = *(const v2f*)&wlds[k4 * 4 + 3][2 * cp];
#pragma unroll
    for (int r = 0; r < 32; ++r) {
      float4 y = *(const float4*)&yin[r][k4 * 4];
      acc[r] += w0 * y.x;  acc[r] += w1 * y.y;
      acc[r] += w2 * y.z;  acc[r] += w3 * y.w;
    }
  }

  v2f bb = *(const v2f*)&blds[2 * cp];
#pragma unroll
  for (int r = 0; r < 32; ++r) {
    size_t base = ((size_t)(tlb + r) * Bb + b) * 768;
    *(v2f*)&Xc[base + 2 * cp] = acc[r] + bb;
  }
}

// ===========================================================================
// P2: aux path for chunk.  Block = (b, 16 t-rows).
// Phase 1: a_m = tanh(aux_m @ auxW_m + auxb_m) -> LDS.
// Phase 2: v_m = a_m @ W_a + b_a (lane-pair K-halves, shfl-xor reduce),
//          emit S3 = sum exp(v_m), N3 = sum exp(v_m)*a_m.
// ===========================================================================
__launch_bounds__(256, 1)
__global__ void p2_aux(const float* __restrict__ aux,
                       const float* __restrict__ auxW, const float* __restrict__ auxb,
                       const float* __restrict__ Wa, const float* __restrict__ ba,
                       float* __restrict__ Xc, int t0) {
  const int b   = blockIdx.x & 127;
  const int tt  = blockIdx.x >> 7;
  const int tg  = t0 + tt * 16;
  const int tlb = tt * 16;
  const int tau = threadIdx.x;

  __shared__ float awlds[3][64][128];  // 96 KB
  __shared__ float ain[3][16][64];     // 12 KB
  __shared__ float am[3][16][128];     // 24 KB
  __shared__ float bstage[512];        // auxb[3][128] + ba[128]

  {
    const float4* src = (const float4*)auxW;
#pragma unroll
    for (int it = 0; it < 24; ++it) {
      int idx = it * 256 + tau;            // 0..6143 float4s
      ((float4*)&awlds[0][0][0])[idx] = src[idx];
    }
#pragma unroll
    for (int m = 0; m < 3; ++m) {
      const float4* as = (const float4*)(aux + (((size_t)m * Bb + b) * Tt + tg) * Ii);
      ((float4*)&ain[m][0][0])[tau] = as[tau];
    }
    if (tau < 128) {
      bstage[0 * 128 + tau] = auxb[0 * 128 + tau];
      bstage[1 * 128 + tau] = auxb[1 * 128 + tau];
      bstage[2 * 128 + tau] = auxb[2 * 128 + tau];
      bstage[384 + tau]     = ba[tau];
    }
  }
  __syncthreads();

  // ---- Phase 1: aux projections + tanh ----
  {
    const int j  = tau & 127;
    const int rh = tau >> 7;            // 8-row half
#pragma unroll
    for (int m = 0; m < 3; ++m) {
      float a8[8];
#pragma unroll
      for (int r = 0; r < 8; ++r) a8[r] = 0.f;
#pragma unroll
      for (int k4 = 0; k4 < 16; ++k4) {
        float w0 = awlds[m][k4 * 4 + 0][j];
        float w1 = awlds[m][k4 * 4 + 1][j];
        float w2 = awlds[m][k4 * 4 + 2][j];
        float w3 = awlds[m][k4 * 4 + 3][j];
#pragma unroll
        for (int r = 0; r < 8; ++r) {
          float4 x = *(const float4*)&ain[m][rh * 8 + r][k4 * 4];
          a8[r] += x.x * w0 + x.y * w1 + x.z * w2 + x.w * w3;
        }
      }
      float bmj = bstage[m * 128 + j];
#pragma unroll
      for (int r = 0; r < 8; ++r) am[m][rh * 8 + r][j] = tanhf(a8[r] + bmj);
    }
  }
  __syncthreads();

  // ---- Phase 2: v_m = a_m @ W_a + b_a ; S3, N3 ----
  {
    const int jj = tau >> 1;     // output col
    const int s2 = tau & 1;      // K half
    v2f wa2[32];
#pragma unroll
    for (int p = 0; p < 32; ++p) {
      int k = s2 * 64 + 2 * p;
      wa2[p] = mk2(Wa[(size_t)k * Hh + jj], Wa[(size_t)(k + 1) * Hh + jj]);
    }
    const float baj = bstage[384 + jj];
#pragma unroll
    for (int r = 0; r < 16; ++r) {
      v2f a0 = mk2(0.f, 0.f), a1 = mk2(0.f, 0.f), a2 = mk2(0.f, 0.f);
#pragma unroll
      for (int k2 = 0; k2 < 32; ++k2) {
        v2f x0 = *(const v2f*)&am[0][r][s2 * 64 + 2 * k2];
        v2f x1 = *(const v2f*)&am[1][r][s2 * 64 + 2 * k2];
        v2f x2 = *(const v2f*)&am[2][r][s2 * 64 + 2 * k2];
        a0 += wa2[k2] * x0;  a1 += wa2[k2] * x1;  a2 += wa2[k2] * x2;
      }
      float v0 = a0.x + a0.y, v1 = a1.x + a1.y, v2 = a2.x + a2.y;
      v0 += __shfl_xor(v0, 1);
      v1 += __shfl_xor(v1, 1);
      v2 += __shfl_xor(v2, 1);
      if (s2 == 0) {
        float e0 = expf(v0 + baj);
        float e1 = expf(v1 + baj);
        float e2 = expf(v2 + baj);
        float S3 = e0 + e1 + e2;
        float N3 = e0 * am[0][r][jj] + e1 * am[1][r][jj] + e2 * am[2][r][jj];
        size_t base = ((size_t)(tlb + r) * Bb + b) * 768;
        Xc[base + 512 + jj] = S3;
        Xc[base + 640 + jj] = N3;
      }
    }
  }
}

// ===========================================================================
// scan3: persistent per-row recurrence, 128 blocks x 1024 threads.
// Phase A: gate dots, K-halves in adjacent lanes (s = tau&1), shfl-xor(1).
// Phase C: C~ @ W_a with 8 K-slices in lanes (r8 = tau&7), butterfly reduce.
// Phase D: softmax-gate + cell update on threads 0..127.  3 barriers/step.
// ===========================================================================
__launch_bounds__(1024, 4)
__global__ void scan3(const float* __restrict__ Xc,
                      const float* __restrict__ Ui, const float* __restrict__ Uf,
                      const float* __restrict__ Uc, const float* __restrict__ Uo,
                      const float* __restrict__ Wa, const float* __restrict__ ba,
                      float* __restrict__ state, float* __restrict__ out,
                      int t0, int Cc) {
  const int b   = blockIdx.x;
  const int tau = threadIdx.x;

  // Phase A mapping
  const int gA = tau >> 8;          // gate 0..3
  const int jA = (tau >> 1) & 127;  // output col
  const int sA = tau & 1;           // K half
  // Phase C mapping
  const int jC = tau >> 3;          // output col
  const int rC = tau & 7;           // K slice (16 wide)
  // Phase D mapping
  const int jD = tau & 127;

  __shared__ float hbuf[Hh];
  __shared__ float act[4][Hh];
  __shared__ float v0buf[Hh];

  const float* Ug = (gA == 0) ? Ui : (gA == 1) ? Uf : (gA == 2) ? Uc : Uo;
  v2f wu[32];
#pragma unroll
  for (int p = 0; p < 32; ++p) {
    int k = sA * 64 + 2 * p;
    wu[p] = mk2(Ug[(size_t)k * Hh + jA], Ug[(size_t)(k + 1) * Hh + jA]);
  }
  v2f wa2[8];
#pragma unroll
  for (int p = 0; p < 8; ++p) {
    int k = rC * 16 + 2 * p;
    wa2[p] = mk2(Wa[(size_t)k * Hh + jC], Wa[(size_t)(k + 1) * Hh + jC]);
  }
  const float ba_j = ba[jD];

  float c = 0.f, h = 0.f;
  if (tau < Hh) {
    if (t0 > 0) { h = state[b * 256 + tau]; c = state[b * 256 + 128 + tau]; }
    hbuf[tau] = h;
  }

  // register prefetch of step-0 x values
  float xg_cur = Xc[((size_t)0 * Bb + b) * 768 + gA * Hh + jA];
  float s3_cur = 0.f, n3_cur = 0.f;
  if (tau < Hh) {
    s3_cur = Xc[((size_t)0 * Bb + b) * 768 + 512 + jD];
    n3_cur = Xc[((size_t)0 * Bb + b) * 768 + 640 + jD];
  }
  __syncthreads();

  for (int tl = 0; tl < Cc; ++tl) {
    // ---- prefetch next step ----
    float xg_nx = 0.f, s3_nx = 0.f, n3_nx = 0.f;
    if (tl + 1 < Cc) {
      size_t nb = ((size_t)(tl + 1) * Bb + b) * 768;
      xg_nx = Xc[nb + gA * Hh + jA];
      if (tau < Hh) { s3_nx = Xc[nb + 512 + jD]; n3_nx = Xc[nb + 640 + jD]; }
    }

    // ---- Phase A: gate dots ----
    v2f acc = mk2(0.f, 0.f);
#pragma unroll
    for (int q4 = 0; q4 < 16; ++q4) {
      float4 h4 = *(const float4*)&hbuf[sA * 64 + q4 * 4];
      acc += wu[2 * q4]     * mk2(h4.x, h4.y);
      acc += wu[2 * q4 + 1] * mk2(h4.z, h4.w);
    }
    float dot = acc.x + acc.y;
    dot += __shfl_xor(dot, 1);         // combine K halves (lane pair)
    if (sA == 0) {
      float pre = dot + xg_cur;        // bias already folded into Xc by P1
      act[gA][jA] = (gA == 2) ? tanhf(pre) : sigmoidf_(pre);
    }
    __syncthreads();  // B1: act ready

    // ---- Phase C: v0 = C~ @ W_a (8 lane-slices) ----
    v2f vacc = mk2(0.f, 0.f);
#pragma unroll
    for (int p4 = 0; p4 < 4; ++p4) {
      float4 c4 = *(const float4*)&act[2][rC * 16 + p4 * 4];
      vacc += wa2[2 * p4]     * mk2(c4.x, c4.y);
      vacc += wa2[2 * p4 + 1] * mk2(c4.z, c4.w);
    }
    float v = vacc.x + vacc.y;
    v += __shfl_xor(v, 1);
    v += __shfl_xor(v, 2);
    v += __shfl_xor(v, 4);
    if (rC == 0) v0buf[jC] = v;
    __syncthreads();  // B2: v0 ready

    // ---- Phase D: softmax-gate + cell update ----
    if (tau < Hh) {
      float e0 = expf(v0buf[jD] + ba_j);
      float ct = act[2][jD];
      float L  = (e0 * ct + n3_cur) / (e0 + s3_cur);
      c = act[1][jD] * c + act[0][jD] * L;
      h = act[3][jD] * tanhf(c);
      hbuf[jD] = h;
      out[16384 + ((size_t)b * Tt + (t0 + tl)) * Hh + jD] = h;
      if (t0 + tl == Tt - 1) out[(size_t)b * Hh + jD] = h;
    }
    __syncthreads();  // B3: hbuf stable for next step

    xg_cur = xg_nx;  s3_cur = s3_nx;  n3_cur = n3_nx;
  }

  if (tau < Hh) {
    state[b * 256 + tau] = h;
    state[b * 256 + 128 + tau] = c;
  }
}

// ===========================================================================
// Fallback (tiny ws): round-1 fused kernel (passed, 6.28 ms).
// ===========================================================================
__launch_bounds__(512, 2)
__global__ void fused_kernel(const float* __restrict__ Y,
                             const float* __restrict__ aux,
                             const float* __restrict__ Wi, const float* __restrict__ Ui,
                             const float* __restrict__ bi,
                             const float* __restrict__ Wf, const float* __restrict__ Uf,
                             const float* __restrict__ bfp,
                             const float* __restrict__ Wc, const float* __restrict__ Uc,
                             const float* __restrict__ bc,
                             const float* __restrict__ Wo, const float* __restrict__ Uo,
                             const float* __restrict__ bo,
                             const float* __restrict__ auxW, const float* __restrict__ auxb,
                             const float* __restrict__ Wa, const float* __restrict__ ba,
                             float* __restrict__ out) {
  const int b   = blockIdx.x;
  const int tau = threadIdx.x;
  const int j   = tau & 127;
  const int q   = tau >> 7;

  __shared__ float wG[4][Ii][Hh];
  __shared__ float xraw[2][4][Ii];
  __shared__ float hbuf[Hh];
  __shared__ float ctl[Hh];
  __shared__ float auxp[3][Hh];
  __shared__ float redG[4][4][Hh];
  __shared__ float redX[3][4][Hh];

  float wU[4][32];
  {
    const float* Us[4] = {Ui, Uf, Uc, Uo};
#pragma unroll
    for (int g = 0; g < 4; ++g)
#pragma unroll
      for (int k = 0; k < 32; ++k)
        wU[g][k] = Us[g][(q * 32 + k) * Hh + j];
  }
  float wA[32];
#pragma unroll
  for (int k = 0; k < 32; ++k) wA[k] = Wa[(q * 32 + k) * Hh + j];
  float wAux[3][16];
#pragma unroll
  for (int m = 0; m < 3; ++m)
#pragma unroll
    for (int k = 0; k < 16; ++k)
      wAux[m][k] = auxW[((size_t)m * Ii + (q * 16 + k)) * Hh + j];
  float bgate[4];
  {
    const float* Bs[4] = {bi, bfp, bc, bo};
#pragma unroll
    for (int g = 0; g < 4; ++g) bgate[g] = Bs[g][j];
  }
  const float abias = (q >= 1) ? auxb[(q - 1) * Hh + j] : 0.f;
  const float ba_j  = ba[j];

  {
    const float* Ws[4] = {Wi, Wf, Wc, Wo};
#pragma unroll
    for (int g = 0; g < 4; ++g) {
      const float4* src = (const float4*)Ws[g];
      float4* dst = (float4*)&wG[g][0][0];
#pragma unroll
      for (int r = 0; r < 4; ++r) dst[tau + r * 512] = src[tau + r * 512];
    }
  }

  if (tau < Hh) hbuf[tau] = 0.f;
  float c = 0.f;

  const bool ldr = (tau < 64);
  const int  m4  = tau >> 4;
  const int  idx = tau & 15;
  const float* srcbase = nullptr;
  float4 xn = make_float4(0.f, 0.f, 0.f, 0.f);
  if (ldr) {
    srcbase = (m4 == 0) ? (Y + ((size_t)b * Tt) * Ii)
                        : (aux + (((size_t)(m4 - 1) * Bb + b) * Tt) * Ii);
    float4 x0 = ((const float4*)srcbase)[idx];
    ((float4*)&xraw[0][0][0])[tau] = x0;
    xn = ((const float4*)(srcbase + Ii))[idx];
  }
  __syncthreads();

  for (int t = 0; t < Tt; ++t) {
    const int p = t & 1;
    float aG0 = 0.f, aG1 = 0.f, aG2 = 0.f, aG3 = 0.f;
#pragma unroll
    for (int kk = 0; kk < 8; ++kk) {
      float4 hv = *(const float4*)&hbuf[q * 32 + kk * 4];
      aG0 += hv.x*wU[0][kk*4] + hv.y*wU[0][kk*4+1] + hv.z*wU[0][kk*4+2] + hv.w*wU[0][kk*4+3];
      aG1 += hv.x*wU[1][kk*4] + hv.y*wU[1][kk*4+1] + hv.z*wU[1][kk*4+2] + hv.w*wU[1][kk*4+3];
      aG2 += hv.x*wU[2][kk*4] + hv.y*wU[2][kk*4+1] + hv.z*wU[2][kk*4+2] + hv.w*wU[2][kk*4+3];
      aG3 += hv.x*wU[3][kk*4] + hv.y*wU[3][kk*4+1] + hv.z*wU[3][kk*4+2] + hv.w*wU[3][kk*4+3];
    }
#pragma unroll
    for (int kk = 0; kk < 4; ++kk) {
      const int k0 = q * 16 + kk * 4;
      float4 yv = *(const float4*)&xraw[p][0][k0];
      aG0 += yv.x*wG[0][k0][j] + yv.y*wG[0][k0+1][j] + yv.z*wG[0][k0+2][j] + yv.w*wG[0][k0+3][j];
      aG1 += yv.x*wG[1][k0][j] + yv.y*wG[1][k0+1][j] + yv.z*wG[1][k0+2][j] + yv.w*wG[1][k0+3][j];
      aG2 += yv.x*wG[2][k0][j] + yv.y*wG[2][k0+1][j] + yv.z*wG[2][k0+2][j] + yv.w*wG[2][k0+3][j];
      aG3 += yv.x*wG[3][k0][j] + yv.y*wG[3][k0+1][j] + yv.z*wG[3][k0+2][j] + yv.w*wG[3][k0+3][j];
    }
    float sA0 = 0.f, sA1 = 0.f, sA2 = 0.f;
#pragma unroll
    for (int kk = 0; kk < 4; ++kk) {
      const int k0 = q * 16 + kk * 4;
      float4 a0v = *(const float4*)&xraw[p][1][k0];
      float4 a1v = *(const float4*)&xraw[p][2][k0];
      float4 a2v = *(const float4*)&xraw[p][3][k0];
      sA0 += a0v.x*wAux[0][kk*4] + a0v.y*wAux[0][kk*4+1] + a0v.z*wAux[0][kk*4+2] + a0v.w*wAux[0][kk*4+3];
      sA1 += a1v.x*wAux[1][kk*4] + a1v.y*wAux[1][kk*4+1] + a1v.z*wAux[1][kk*4+2] + a1v.w*wAux[1][kk*4+3];
      sA2 += a2v.x*wAux[2][kk*4] + a2v.y*wAux[2][kk*4+1] + a2v.z*wAux[2][kk*4+2] + a2v.w*wAux[2][kk*4+3];
    }
    redG[0][q][j] = aG0;  redG[1][q][j] = aG1;
    redG[2][q][j] = aG2;  redG[3][q][j] = aG3;
    redX[0][q][j] = sA0;  redX[1][q][j] = sA1;  redX[2][q][j] = sA2;
    __syncthreads();

    if (q == 0) {
      float pi = bgate[0] + redG[0][0][j] + redG[0][1][j] + redG[0][2][j] + redG[0][3][j];
      float pf = bgate[1] + redG[1][0][j] + redG[1][1][j] + redG[1][2][j] + redG[1][3][j];
      float pc = bgate[2] + redG[2][0][j] + redG[2][1][j] + redG[2][2][j] + redG[2][3][j];
      float po = bgate[3] + redG[3][0][j] + redG[3][1][j] + redG[3][2][j] + redG[3][3][j];
      float ig = sigmoidf_(pi);
      float fg = sigmoidf_(pf);
      float og = sigmoidf_(po);
      ctl[j] = tanhf(pc);
      redG[0][0][j] = ig;  redG[1][0][j] = fg;  redG[3][0][j] = og;
    } else {
      const int m = q - 1;
      float v = abias + redX[m][0][j] + redX[m][1][j] + redX[m][2][j] + redX[m][3][j];
      auxp[m][j] = tanhf(v);
    }
    if (ldr) {
      ((float4*)&xraw[p ^ 1][0][0])[tau] = xn;
      if (t + 2 < Tt) xn = ((const float4*)(srcbase + (size_t)(t + 2) * Ii))[idx];
    }
    __syncthreads();

    float sS0 = 0.f, sS1 = 0.f, sS2 = 0.f, sS3 = 0.f;
#pragma unroll
    for (int kk = 0; kk < 8; ++kk) {
      const int k0 = q * 32 + kk * 4;
      float4 c0 = *(const float4*)&ctl[k0];
      float4 c1 = *(const float4*)&auxp[0][k0];
      float4 c2 = *(const float4*)&auxp[1][k0];
      float4 c3 = *(const float4*)&auxp[2][k0];
      sS0 += c0.x*wA[kk*4] + c0.y*wA[kk*4+1] + c0.z*wA[kk*4+2] + c0.w*wA[kk*4+3];
      sS1 += c1.x*wA[kk*4] + c1.y*wA[kk*4+1] + c1.z*wA[kk*4+2] + c1.w*wA[kk*4+3];
      sS2 += c2.x*wA[kk*4] + c2.y*wA[kk*4+1] + c2.z*wA[kk*4+2] + c2.w*wA[kk*4+3];
      sS3 += c3.x*wA[kk*4] + c3.y*wA[kk*4+1] + c3.z*wA[kk*4+2] + c3.w*wA[kk*4+3];
    }
    __syncthreads();
    redX[0][q][j] = sS1;  redX[1][q][j] = sS2;  redX[2][q][j] = sS3;
    redG[2][q][j] = sS0;
    __syncthreads();

    if (q == 0) {
      float v0 = ba_j + redG[2][0][j] + redG[2][1][j] + redG[2][2][j] + redG[2][3][j];
      float v1 = ba_j + redX[0][0][j] + redX[0][1][j] + redX[0][2][j] + redX[0][3][j];
      float v2 = ba_j + redX[1][0][j] + redX[1][1][j] + redX[1][2][j] + redX[1][3][j];
      float v3 = ba_j + redX[2][0][j] + redX[2][1][j] + redX[2][2][j] + redX[2][3][j];
      float mx = fmaxf(fmaxf(v0, v1), fmaxf(v2, v3));
      float e0 = expf(v0 - mx), e1 = expf(v1 - mx), e2 = expf(v2 - mx), e3 = expf(v3 - mx);
      float inv = 1.f / (e0 + e1 + e2 + e3);
      float L = (e0 * ctl[j] + e1 * auxp[0][j] + e2 * auxp[1][j] + e3 * auxp[2][j]) * inv;
      float ig = redG[0][0][j], fg = redG[1][0][j], og = redG[3][0][j];
      c = fg * c + ig * L;
      float h = og * tanhf(c);
      hbuf[j] = h;
      out[16384 + ((size_t)b * Tt + t) * Hh + j] = h;
      if (t == Tt - 1) out[(size_t)b * Hh + j] = h;
    }
    __syncthreads();
  }
}

// ===========================================================================
extern "C" void kernel_launch(void* const* d_in, const int* in_sizes, int n_in,
                              void* d_out, int out_size, void* d_ws, size_t ws_size,
                              hipStream_t stream) {
  (void)in_sizes; (void)n_in; (void)out_size;
  const float* Y     = (const float*)d_in[0];
  const float* aux   = (const float*)d_in[1];
  const float* W_i   = (const float*)d_in[2];
  const float* U_i   = (const float*)d_in[3];
  const float* b_i   = (const float*)d_in[4];
  const float* W_f   = (const float*)d_in[5];
  const float* U_f   = (const float*)d_in[6];
  const float* b_f   = (const float*)d_in[7];
  const float* W_c   = (const float*)d_in[8];
  const float* U_c   = (const float*)d_in[9];
  const float* b_c   = (const float*)d_in[10];
  const float* W_o   = (const float*)d_in[11];
  const float* U_o   = (const float*)d_in[12];
  const float* b_o   = (const float*)d_in[13];
  const float* aux_W = (const float*)d_in[14];
  const float* aux_b = (const float*)d_in[15];
  const float* W_a   = (const float*)d_in[16];
  const float* b_a   = (const float*)d_in[17];
  float* out = (float*)d_out;

  // chunk size C: Xc = C*128*768*4 bytes, plus 128 KB state
  int C = 0;
  const int cands[4] = {512, 256, 128, 64};
  for (int i = 0; i < 4; ++i) {
    size_t need = (size_t)cands[i] * Bb * 768 * sizeof(float) + 131072;
    if (d_ws != nullptr && ws_size >= need) { C = cands[i]; break; }
  }

  if (C > 0) {
    float* Xc    = (float*)d_ws;
    float* state = (float*)((char*)d_ws + (size_t)C * Bb * 768 * sizeof(float));
    for (int t0 = 0; t0 < Tt; t0 += C) {
      int Cc = (Tt - t0 < C) ? (Tt - t0) : C;
      p1_gates<<<dim3(Bb * (Cc / 32)), dim3(256), 0, stream>>>(
          Y, W_i, W_f, W_c, W_o, b_i, b_f, b_c, b_o, Xc, t0);
      p2_aux<<<dim3(Bb * (Cc / 16)), dim3(256), 0, stream>>>(
          aux, aux_W, aux_b, W_a, b_a, Xc, t0);
      scan3<<<dim3(Bb), dim3(1024), 0, stream>>>(
          Xc, U_i, U_f, U_c, U_o, W_a, b_a, state, out, t0, Cc);
    }
  } else {
    fused_kernel<<<dim3(Bb), dim3(512), 0, stream>>>(
        Y, aux, W_i, U_i, b_i, W_f, U_f, b_f, W_c, U_c, b_c,
        W_o, U_o, b_o, aux_W, aux_b, W_a, b_a, out);
  }
}